// Round 1
// baseline (1420.353 us; speedup 1.0000x reference)
//
#include <hip/hip_runtime.h>
#include <hip/hip_bf16.h>
#include <math.h>

#define N_NODES 40000
#define N_EDGES 640000
#define HID 128
#define MAXW 64      // in-degree ~ Poisson(16); P(deg > 64) ~ 1e-19 -> never drops edges
#define ITERS 8      // full iterations after initial state = tanh(xproj)

__global__ __launch_bounds__(256) void zero_deg_kernel(int* deg) {
    int i = blockIdx.x * 256 + threadIdx.x;
    if (i < N_NODES) deg[i] = 0;
}

__global__ __launch_bounds__(256) void build_ell_kernel(const int* __restrict__ ei,
                                                        int* __restrict__ deg,
                                                        int* __restrict__ ell) {
    int e = blockIdx.x * 256 + threadIdx.x;
    if (e >= N_EDGES) return;
    int s = ei[e];            // src
    int d = ei[N_EDGES + e];  // dst
    int c = atomicAdd(&deg[d], 1);
    if (c < MAXW) ell[d * MAXW + c] = s;
}

__global__ __launch_bounds__(256) void transpose_kernel(const float* __restrict__ w,
                                                        float* __restrict__ wt) {
    int t = blockIdx.x * 256 + threadIdx.x;  // 16384 threads
    int j = t >> 7, k = t & 127;
    wt[k * HID + j] = w[j * HID + k];        // wt[k][j] = w[j][k]
}

// aggr[n,:] = sum over incoming edges (src s) of state[s,:]
// one wave per node; lane holds float2 (features 2*lane, 2*lane+1)
__global__ __launch_bounds__(256) void agg_kernel(const float* __restrict__ state,
                                                  const int* __restrict__ ell,
                                                  const int* __restrict__ deg,
                                                  float* __restrict__ aggr) {
    int node = blockIdx.x * 4 + (threadIdx.x >> 6);
    int lane = threadIdx.x & 63;
    if (node >= N_NODES) return;
    int cnt = deg[node];
    if (cnt > MAXW) cnt = MAXW;
    int myidx = (lane < cnt) ? ell[node * MAXW + lane] : 0;
    float ax = 0.f, ay = 0.f;
    for (int i = 0; i < cnt; ++i) {
        int s = __shfl(myidx, i);
        const float2 v = *(const float2*)(state + (size_t)s * HID + lane * 2);
        ax += v.x;
        ay += v.y;
    }
    float2 o; o.x = ax; o.y = ay;
    *(float2*)(aggr + (size_t)node * HID + lane * 2) = o;
}

// out_state[n,j] = tanh(bias[n,j] + sum_k in[n,k] * W[k,j]); optionally also
// store the pre-tanh value to out_raw (xproj mode). BM=64, BN=128, BK=64.
// NOTE: `in` may alias `out_state` (layer-1 xproj reads h0 from d_out while
// writing tanh(xproj1) back to d_out) -> no __restrict__ on those two. Safe
// because each block reads only its own rows, fully staged before epilogue.
__global__ __launch_bounds__(256) void gemm_kernel(const float* in,
                                                   const float* __restrict__ W,
                                                   const float* __restrict__ bias,
                                                   float* __restrict__ out_raw,
                                                   float* out_state) {
    __shared__ float w_lds[64][HID];     // 32 KB per K-chunk
    __shared__ float a_lds[64][68];      // [k][row], +4 pad; 17.4 KB
    int tid = threadIdx.x;
    int n0 = blockIdx.x * 64;
    int tj = tid & 15;   // 16 col groups x 8 cols
    int ti = tid >> 4;   // 16 row groups x 4 rows
    float acc[4][8];
#pragma unroll
    for (int r = 0; r < 4; r++)
#pragma unroll
        for (int c = 0; c < 8; c++) acc[r][c] = 0.f;

    for (int kt = 0; kt < HID; kt += 64) {
        // stage W chunk: 64x128 floats = 2048 float4, 8 per thread
#pragma unroll
        for (int i = 0; i < 8; i++) {
            int f = tid + 256 * i;
            int kk = f >> 5;
            int jj = (f & 31) << 2;
            *(float4*)&w_lds[kk][jj] = *(const float4*)&W[(kt + kk) * HID + jj];
        }
        // stage A chunk transposed: rows n0..n0+63, k in [kt, kt+64)
        {
            int r = tid >> 2;
            int c4 = (tid & 3) << 4;
#pragma unroll
            for (int i = 0; i < 4; i++) {
                float4 v = *(const float4*)&in[(size_t)(n0 + r) * HID + kt + c4 + i * 4];
                a_lds[c4 + i * 4 + 0][r] = v.x;
                a_lds[c4 + i * 4 + 1][r] = v.y;
                a_lds[c4 + i * 4 + 2][r] = v.z;
                a_lds[c4 + i * 4 + 3][r] = v.w;
            }
        }
        __syncthreads();
#pragma unroll
        for (int kk = 0; kk < 64; ++kk) {
            float4 a = *(float4*)&a_lds[kk][ti * 4];
            float4 b0 = *(float4*)&w_lds[kk][tj * 8];
            float4 b1 = *(float4*)&w_lds[kk][tj * 8 + 4];
            float av[4] = {a.x, a.y, a.z, a.w};
            float bv[8] = {b0.x, b0.y, b0.z, b0.w, b1.x, b1.y, b1.z, b1.w};
#pragma unroll
            for (int r = 0; r < 4; r++)
#pragma unroll
                for (int c = 0; c < 8; c++)
                    acc[r][c] = fmaf(av[r], bv[c], acc[r][c]);
        }
        __syncthreads();
    }

#pragma unroll
    for (int r = 0; r < 4; r++) {
        int n = n0 + ti * 4 + r;
        size_t off = (size_t)n * HID + tj * 8;
        float v[8];
#pragma unroll
        for (int c = 0; c < 8; c++) v[c] = acc[r][c];
        if (bias) {
            float4 b0 = *(const float4*)(bias + off);
            float4 b1 = *(const float4*)(bias + off + 4);
            v[0] += b0.x; v[1] += b0.y; v[2] += b0.z; v[3] += b0.w;
            v[4] += b1.x; v[5] += b1.y; v[6] += b1.z; v[7] += b1.w;
        }
        if (out_raw) {
            float4 r0 = {v[0], v[1], v[2], v[3]};
            float4 r1 = {v[4], v[5], v[6], v[7]};
            *(float4*)(out_raw + off) = r0;
            *(float4*)(out_raw + off + 4) = r1;
        }
        float4 t0 = {tanhf(v[0]), tanhf(v[1]), tanhf(v[2]), tanhf(v[3])};
        float4 t1 = {tanhf(v[4]), tanhf(v[5]), tanhf(v[6]), tanhf(v[7])};
        *(float4*)(out_state + off) = t0;
        *(float4*)(out_state + off + 4) = t1;
    }
}

extern "C" void kernel_launch(void* const* d_in, const int* in_sizes, int n_in,
                              void* d_out, int out_size, void* d_ws, size_t ws_size,
                              hipStream_t stream) {
    const int* ei = (const int*)d_in[0];       // edge_index [2][E]
    const float* x = (const float*)d_in[1];    // [N][128]
    const float* w_in0 = (const float*)d_in[2];
    const float* w_rec0 = (const float*)d_in[3];
    const float* w_in1 = (const float*)d_in[4];
    const float* w_rec1 = (const float*)d_in[5];
    float* out = (float*)d_out;                // state buffer; ends as h1

    // workspace carve (needs ~49 MB)
    float* xproj = (float*)d_ws;                       // N*HID
    float* aggr = xproj + (size_t)N_NODES * HID;       // N*HID
    float* wt = aggr + (size_t)N_NODES * HID;          // HID*HID
    int* deg = (int*)(wt + HID * HID);                 // N
    int* ell = deg + N_NODES;                          // N*MAXW

    // build dst-bucketed ELL adjacency (once per call; ws is re-poisoned)
    zero_deg_kernel<<<(N_NODES + 255) / 256, 256, 0, stream>>>(deg);
    build_ell_kernel<<<(N_EDGES + 255) / 256, 256, 0, stream>>>(ei, deg, ell);

    for (int layer = 0; layer < 2; ++layer) {
        const float* w_in = layer ? w_in1 : w_in0;
        const float* w_rec = layer ? w_rec1 : w_rec0;
        const float* src_in = layer ? out : x;  // layer1 input = h0 (in d_out)
        transpose_kernel<<<64, 256, 0, stream>>>(w_in, wt);
        // xproj = src_in @ w_in^T ; state = tanh(xproj)  (== first update)
        gemm_kernel<<<625, 256, 0, stream>>>(src_in, wt, nullptr, xproj, out);
        for (int it = 0; it < ITERS; ++it) {
            agg_kernel<<<10000, 256, 0, stream>>>(out, ell, deg, aggr);
            gemm_kernel<<<625, 256, 0, stream>>>(aggr, w_rec, xproj, nullptr, out);
        }
    }
}

// Round 2
// 1123.371 us; speedup vs baseline: 1.2644x; 1.2644x over previous
//
#include <hip/hip_runtime.h>
#include <math.h>

#define N_NODES 40000
#define N_EDGES 640000
#define HID 128
#define MAXW 64      // in-degree ~ Poisson(16); P(deg > 64) ~ 1e-19 -> never drops edges
#define ITERS 8      // full iterations after initial state = tanh(xproj)
#define NH (N_NODES * HID)

typedef __bf16 bf16x8 __attribute__((ext_vector_type(8)));
typedef __bf16 bf16x4 __attribute__((ext_vector_type(4)));
typedef __bf16 bf16x2 __attribute__((ext_vector_type(2)));
typedef float floatx4 __attribute__((ext_vector_type(4)));

__global__ __launch_bounds__(256) void zero_deg_kernel(int* deg) {
    int i = blockIdx.x * 256 + threadIdx.x;
    if (i < N_NODES) deg[i] = 0;
}

__global__ __launch_bounds__(256) void build_ell_kernel(const int* __restrict__ ei,
                                                        int* __restrict__ deg,
                                                        int* __restrict__ ell) {
    int e = blockIdx.x * 256 + threadIdx.x;
    if (e >= N_EDGES) return;
    int s = ei[e];            // src
    int d = ei[N_EDGES + e];  // dst
    int c = atomicAdd(&deg[d], 1);
    if (c < MAXW) ell[d * MAXW + c] = s;
}

// Pack W (or W^T) into B-fragment order for mfma_f32_16x16x32_bf16:
// pk[((c*8+t)*64 + lane)*8 + j] = B[k = c*32 + (lane>>4)*8 + j][n = t*16 + (lane&15)]
// where B[k][n] = trans ? w[n][k] : w[k][n].
__global__ __launch_bounds__(256) void pack_w_kernel(const float* __restrict__ w,
                                                     __bf16* __restrict__ pk, int trans) {
    int f = blockIdx.x * 256 + threadIdx.x;  // 16384 total
    int j = f & 7, l = (f >> 3) & 63, t = (f >> 9) & 7, c = f >> 12;
    int k = c * 32 + (l >> 4) * 8 + j;
    int n = t * 16 + (l & 15);
    float v = trans ? w[n * HID + k] : w[k * HID + n];
    pk[f] = (__bf16)v;
}

__global__ __launch_bounds__(256) void cast_bf16_kernel(const float* __restrict__ x,
                                                        __bf16* __restrict__ o) {
    int i = blockIdx.x * 256 + threadIdx.x;   // 1.28M threads, 4 elems each
    float4 v = ((const float4*)x)[i];
    bf16x4 b;
    b[0] = (__bf16)v.x; b[1] = (__bf16)v.y; b[2] = (__bf16)v.z; b[3] = (__bf16)v.w;
    ((bf16x4*)o)[i] = b;
}

// aggr[n,:] = sum over incoming edges of state[src,:]  (bf16 rows, fp32 accum)
// one wave per node; lane owns features {2*lane, 2*lane+1}; 64 lanes x 4B = 256B row.
__global__ __launch_bounds__(256) void agg_kernel(const __bf16* __restrict__ state,
                                                  const int* __restrict__ ell,
                                                  const int* __restrict__ deg,
                                                  __bf16* __restrict__ aggr) {
    int node = blockIdx.x * 4 + (threadIdx.x >> 6);
    int lane = threadIdx.x & 63;
    int cnt = deg[node];
    if (cnt > MAXW) cnt = MAXW;
    int myidx = (lane < cnt) ? ell[node * MAXW + lane] : 0;
    float ax = 0.f, ay = 0.f;
    for (int i = 0; i < cnt; ++i) {
        int s = __shfl(myidx, i);
        bf16x2 v = *(const bf16x2*)(state + (size_t)s * HID + lane * 2);
        ax += (float)v[0];
        ay += (float)v[1];
    }
    bf16x2 o;
    o[0] = (__bf16)ax; o[1] = (__bf16)ay;
    *(bf16x2*)(aggr + (size_t)node * HID + lane * 2) = o;
}

// out = tanh(bias + A @ B), A:[40000][128] bf16 row-major, B packed (see pack_w).
// Block = 256 threads (4 waves); wave w owns rows blockIdx*64 + w*16 .. +16.
// Full N=128 per wave as 8 n-tiles; K=128 as 4 chunks of mfma_f32_16x16x32_bf16.
// Fragment layouts (m89/m91-verified): A[m=lane&15][k=(lane>>4)*8+j],
// B[k=(lane>>4)*8+j][n=lane&15], D[row=(lane>>4)*4+r][col=lane&15].
// NOTE: A may alias st_bf (layer-1 xproj reads h0 while writing state) -> no
// __restrict__ on those two. Safe: each wave reads only its own 16 rows, fully
// consumed by MFMA before the epilogue stores to the same 16 rows.
__global__ __launch_bounds__(256) void mfma_gemm_kernel(const __bf16* A,
                                                        const __bf16* __restrict__ Bpk,
                                                        const float* __restrict__ bias,
                                                        float* __restrict__ raw_out,
                                                        __bf16* st_bf,
                                                        float* __restrict__ st_f32) {
    int tid = threadIdx.x;
    int wv = tid >> 6, lane = tid & 63;
    int q = lane >> 4, cl = lane & 15;

    int row_a = blockIdx.x * 64 + wv * 16 + cl;
    bf16x8 a[4];
#pragma unroll
    for (int c = 0; c < 4; ++c)
        a[c] = *(const bf16x8*)(A + (size_t)row_a * HID + c * 32 + q * 8);

    floatx4 acc[8];
#pragma unroll
    for (int t = 0; t < 8; ++t) {
        floatx4 acc_t = {0.f, 0.f, 0.f, 0.f};
#pragma unroll
        for (int c = 0; c < 4; ++c) {
            bf16x8 b = *(const bf16x8*)(Bpk + (((c * 8 + t) * 64 + lane) << 3));
            acc_t = __builtin_amdgcn_mfma_f32_16x16x32_bf16(a[c], b, acc_t, 0, 0, 0);
        }
        acc[t] = acc_t;
    }

    int row_d0 = blockIdx.x * 64 + wv * 16 + q * 4;
#pragma unroll
    for (int t = 0; t < 8; ++t) {
        int col = t * 16 + cl;
#pragma unroll
        for (int r = 0; r < 4; ++r) {
            size_t off = (size_t)(row_d0 + r) * HID + col;
            float v = acc[t][r];
            if (bias) v += bias[off];
            if (raw_out) raw_out[off] = v;
            float s = tanhf(v);
            st_bf[off] = (__bf16)s;
            if (st_f32) st_f32[off] = s;
        }
    }
}

extern "C" void kernel_launch(void* const* d_in, const int* in_sizes, int n_in,
                              void* d_out, int out_size, void* d_ws, size_t ws_size,
                              hipStream_t stream) {
    const int* ei = (const int*)d_in[0];       // edge_index [2][E]
    const float* x = (const float*)d_in[1];    // [N][128] f32
    const float* w_in0 = (const float*)d_in[2];
    const float* w_rec0 = (const float*)d_in[3];
    const float* w_in1 = (const float*)d_in[4];
    const float* w_rec1 = (const float*)d_in[5];
    float* out = (float*)d_out;

    // workspace carve (~51.5 MB total)
    float* xproj = (float*)d_ws;                 // NH f32 (20.48 MB)
    __bf16* state_bf = (__bf16*)(xproj + NH);    // NH bf16 (10.24 MB)
    __bf16* aggr_bf = state_bf + NH;             // NH bf16 (10.24 MB); doubles as x_bf
    __bf16* packs = aggr_bf + NH;                // 4 x 16384 bf16 (128 KB)
    int* deg = (int*)(packs + 4 * 16384);        // N
    int* ell = deg + N_NODES;                    // N*MAXW (10.24 MB)
    __bf16* pk_in0 = packs;
    __bf16* pk_rec0 = packs + 16384;
    __bf16* pk_in1 = packs + 2 * 16384;
    __bf16* pk_rec1 = packs + 3 * 16384;

    zero_deg_kernel<<<(N_NODES + 255) / 256, 256, 0, stream>>>(deg);
    build_ell_kernel<<<(N_EDGES + 255) / 256, 256, 0, stream>>>(ei, deg, ell);
    pack_w_kernel<<<64, 256, 0, stream>>>(w_in0, pk_in0, 1);   // B = w_in0^T
    pack_w_kernel<<<64, 256, 0, stream>>>(w_rec0, pk_rec0, 0); // B = w_rec0
    pack_w_kernel<<<64, 256, 0, stream>>>(w_in1, pk_in1, 1);
    pack_w_kernel<<<64, 256, 0, stream>>>(w_rec1, pk_rec1, 0);
    cast_bf16_kernel<<<NH / 4 / 256, 256, 0, stream>>>(x, aggr_bf);  // x_bf in aggr slot

    // ---- layer 0 ----
    // xproj0 = x @ w_in0^T (raw, f32) ; state = tanh(xproj0)
    mfma_gemm_kernel<<<625, 256, 0, stream>>>(aggr_bf, pk_in0, nullptr, xproj,
                                              state_bf, nullptr);
    for (int it = 0; it < ITERS; ++it) {
        agg_kernel<<<N_NODES / 4, 256, 0, stream>>>(state_bf, ell, deg, aggr_bf);
        mfma_gemm_kernel<<<625, 256, 0, stream>>>(aggr_bf, pk_rec0, xproj, nullptr,
                                                  state_bf, nullptr);
    }
    // ---- layer 1 ----
    // xproj1 = h0 @ w_in1^T ; state = tanh(xproj1)   (A aliases st_bf: safe, see kernel)
    mfma_gemm_kernel<<<625, 256, 0, stream>>>(state_bf, pk_in1, nullptr, xproj,
                                              state_bf, nullptr);
    for (int it = 0; it < ITERS; ++it) {
        agg_kernel<<<N_NODES / 4, 256, 0, stream>>>(state_bf, ell, deg, aggr_bf);
        float* f32out = (it == ITERS - 1) ? out : nullptr;
        mfma_gemm_kernel<<<625, 256, 0, stream>>>(aggr_bf, pk_rec1, xproj, nullptr,
                                                  state_bf, f32out);
    }
}

// Round 3
// 725.120 us; speedup vs baseline: 1.9588x; 1.5492x over previous
//
#include <hip/hip_runtime.h>
#include <math.h>

#define N_NODES 40000
#define N_EDGES 640000
#define HID 128
#define MAXW 64      // in-degree ~ Poisson(16); P(deg > 64) ~ 1e-19 -> never drops edges
#define ITERS 8      // full iterations after initial state = tanh(xproj)
#define NH (N_NODES * HID)

typedef __bf16 bf16x8 __attribute__((ext_vector_type(8)));
typedef __bf16 bf16x4 __attribute__((ext_vector_type(4)));
typedef float floatx4 __attribute__((ext_vector_type(4)));

// Fill ELL with pad index N_NODES, zero deg, zero the state pad row.
__global__ __launch_bounds__(256) void init_kernel(int* __restrict__ ell,
                                                   int* __restrict__ deg,
                                                   __bf16* __restrict__ state_pad) {
    int i = blockIdx.x * 256 + threadIdx.x;   // grid covers 640000 threads
    int4 pad = {N_NODES, N_NODES, N_NODES, N_NODES};
    ((int4*)ell)[i] = pad;                    // N*MAXW/4 = 640000 int4 exactly
    if (i < N_NODES) deg[i] = 0;
    if (i < HID / 8) {
        bf16x8 z;
#pragma unroll
        for (int j = 0; j < 8; ++j) z[j] = (__bf16)0.f;
        ((bf16x8*)state_pad)[i] = z;
    }
}

__global__ __launch_bounds__(256) void build_ell_kernel(const int* __restrict__ ei,
                                                        int* __restrict__ deg,
                                                        int* __restrict__ ell) {
    int e = blockIdx.x * 256 + threadIdx.x;
    if (e >= N_EDGES) return;
    int s = ei[e];            // src
    int d = ei[N_EDGES + e];  // dst
    int c = atomicAdd(&deg[d], 1);
    if (c < MAXW) ell[d * MAXW + c] = s;
}

// Pack W (or W^T) into B-fragment order for mfma_f32_16x16x32_bf16:
// pk[((c*8+t)*64 + lane)*8 + j] = B[k = c*32 + (lane>>4)*8 + j][n = t*16 + (lane&15)]
__global__ __launch_bounds__(256) void pack_w_kernel(const float* __restrict__ w,
                                                     __bf16* __restrict__ pk, int trans) {
    int f = blockIdx.x * 256 + threadIdx.x;  // 16384 total
    int j = f & 7, l = (f >> 3) & 63, t = (f >> 9) & 7, c = f >> 12;
    int k = c * 32 + (l >> 4) * 8 + j;
    int n = t * 16 + (l & 15);
    float v = trans ? w[n * HID + k] : w[k * HID + n];
    pk[f] = (__bf16)v;
}

__global__ __launch_bounds__(256) void cast_bf16_kernel(const float* __restrict__ x,
                                                        __bf16* __restrict__ o) {
    int i = blockIdx.x * 256 + threadIdx.x;   // NH/4 threads
    float4 v = ((const float4*)x)[i];
    bf16x4 b;
    b[0] = (__bf16)v.x; b[1] = (__bf16)v.y; b[2] = (__bf16)v.z; b[3] = (__bf16)v.w;
    ((bf16x4*)o)[i] = b;
}

// aggr[n,:] = sum over incoming edges of state[src,:].
// One wave per node, split into 4 quarter-waves: lane = (q<<4)|f, q=quarter,
// f=0..15. Lane loads bf16x8 (16B) so 16 lanes cover one 256B row; quarter q
// handles edge slots i*4+q. 4 loop steps batched -> 4 outstanding loads/wave
// (fixes the round-2 latency serialization: 1 load in flight -> 4, and 4x
// fewer VMEM instructions). ELL is padded with N_NODES -> zero row, so no
// bounds masking in the hot loop. Cross-quarter butterfly merges partials.
__global__ __launch_bounds__(256) void agg_kernel(const __bf16* __restrict__ state,
                                                  const int* __restrict__ ell,
                                                  const int* __restrict__ deg,
                                                  __bf16* __restrict__ aggr) {
    int node = blockIdx.x * 4 + (threadIdx.x >> 6);
    int lane = threadIdx.x & 63;
    int q = lane >> 4, f = lane & 15;
    int cnt = deg[node];
    if (cnt > MAXW) cnt = MAXW;
    int myidx = ell[node * MAXW + lane];   // padded beyond cnt
    float acc[8];
#pragma unroll
    for (int j = 0; j < 8; ++j) acc[j] = 0.f;
    int iters = (cnt + 3) >> 2;            // groups of 4 edges; <=16
    for (int i0 = 0; i0 < iters; i0 += 4) {
        int base = i0 * 4 + q;             // slots <= 63 always
        int s0 = __shfl(myidx, base);
        int s1 = __shfl(myidx, base + 4);
        int s2 = __shfl(myidx, base + 8);
        int s3 = __shfl(myidx, base + 12);
        bf16x8 v0 = *(const bf16x8*)(state + (size_t)s0 * HID + f * 8);
        bf16x8 v1 = *(const bf16x8*)(state + (size_t)s1 * HID + f * 8);
        bf16x8 v2 = *(const bf16x8*)(state + (size_t)s2 * HID + f * 8);
        bf16x8 v3 = *(const bf16x8*)(state + (size_t)s3 * HID + f * 8);
#pragma unroll
        for (int j = 0; j < 8; ++j)
            acc[j] += ((float)v0[j] + (float)v1[j]) + ((float)v2[j] + (float)v3[j]);
    }
#pragma unroll
    for (int j = 0; j < 8; ++j) {
        acc[j] += __shfl_xor(acc[j], 16);
        acc[j] += __shfl_xor(acc[j], 32);
    }
    if (q == 0) {
        bf16x8 o;
#pragma unroll
        for (int j = 0; j < 8; ++j) o[j] = (__bf16)acc[j];
        *(bf16x8*)(aggr + (size_t)node * HID + f * 8) = o;
    }
}

// out = tanh(bias + A @ B). Same MFMA core as round 2; epilogue now stages the
// wave's 16x128 f32 tile through LDS (wave-private -> no barrier; stride 132
// pads to 2-way banking which is free) so all global epilogue traffic is
// float4/16B vectorized instead of 32 scalar loads + 32 scalar 2B stores.
__global__ __launch_bounds__(256) void mfma_gemm_kernel(const __bf16* A,
                                                        const __bf16* __restrict__ Bpk,
                                                        const float* __restrict__ bias,
                                                        float* __restrict__ raw_out,
                                                        __bf16* st_bf,
                                                        float* __restrict__ st_f32) {
    __shared__ float tile[4][16][132];     // 33792 B
    int tid = threadIdx.x;
    int wv = tid >> 6, lane = tid & 63;
    int q = lane >> 4, cl = lane & 15;

    int row_a = blockIdx.x * 64 + wv * 16 + cl;
    bf16x8 a[4];
#pragma unroll
    for (int c = 0; c < 4; ++c)
        a[c] = *(const bf16x8*)(A + (size_t)row_a * HID + c * 32 + q * 8);

#pragma unroll
    for (int t = 0; t < 8; ++t) {
        floatx4 acc_t = {0.f, 0.f, 0.f, 0.f};
#pragma unroll
        for (int c = 0; c < 4; ++c) {
            bf16x8 b = *(const bf16x8*)(Bpk + (((c * 8 + t) * 64 + lane) << 3));
            acc_t = __builtin_amdgcn_mfma_f32_16x16x32_bf16(a[c], b, acc_t, 0, 0, 0);
        }
        // stage D-layout: row=q*4+r, col=t*16+cl
#pragma unroll
        for (int r = 0; r < 4; ++r)
            tile[wv][q * 4 + r][t * 16 + cl] = acc_t[r];
    }
    // wave-private LDS region: same-wave DS ordering + compiler lgkmcnt waits
    int row = lane >> 2;          // 0..15
    int seg = lane & 3;           // cols seg*32 .. seg*32+31
    size_t goff = (size_t)(blockIdx.x * 64 + wv * 16 + row) * HID + seg * 32;
    float v[32];
#pragma unroll
    for (int j = 0; j < 8; ++j) {
        floatx4 t4 = *(floatx4*)&tile[wv][row][seg * 32 + j * 4];
        v[j * 4 + 0] = t4[0]; v[j * 4 + 1] = t4[1];
        v[j * 4 + 2] = t4[2]; v[j * 4 + 3] = t4[3];
    }
    if (bias) {
#pragma unroll
        for (int j = 0; j < 8; ++j) {
            float4 b = *(const float4*)(bias + goff + j * 4);
            v[j * 4 + 0] += b.x; v[j * 4 + 1] += b.y;
            v[j * 4 + 2] += b.z; v[j * 4 + 3] += b.w;
        }
    }
    if (raw_out) {
#pragma unroll
        for (int j = 0; j < 8; ++j) {
            float4 o = {v[j * 4], v[j * 4 + 1], v[j * 4 + 2], v[j * 4 + 3]};
            *(float4*)(raw_out + goff + j * 4) = o;
        }
    }
#pragma unroll
    for (int i = 0; i < 32; ++i) v[i] = tanhf(v[i]);
#pragma unroll
    for (int j = 0; j < 4; ++j) {
        bf16x8 o;
#pragma unroll
        for (int k = 0; k < 8; ++k) o[k] = (__bf16)v[j * 8 + k];
        *(bf16x8*)(st_bf + goff + j * 8) = o;
    }
    if (st_f32) {
#pragma unroll
        for (int j = 0; j < 8; ++j) {
            float4 o = {v[j * 4], v[j * 4 + 1], v[j * 4 + 2], v[j * 4 + 3]};
            *(float4*)(st_f32 + goff + j * 4) = o;
        }
    }
}

extern "C" void kernel_launch(void* const* d_in, const int* in_sizes, int n_in,
                              void* d_out, int out_size, void* d_ws, size_t ws_size,
                              hipStream_t stream) {
    const int* ei = (const int*)d_in[0];       // edge_index [2][E]
    const float* x = (const float*)d_in[1];    // [N][128] f32
    const float* w_in0 = (const float*)d_in[2];
    const float* w_rec0 = (const float*)d_in[3];
    const float* w_in1 = (const float*)d_in[4];
    const float* w_rec1 = (const float*)d_in[5];
    float* out = (float*)d_out;

    // workspace carve (~51.5 MB total)
    float* xproj = (float*)d_ws;                   // NH f32 (20.48 MB)
    __bf16* state_bf = (__bf16*)(xproj + NH);      // NH + HID bf16 (pad row at end)
    __bf16* aggr_bf = state_bf + NH + HID;         // NH bf16; doubles as x_bf
    __bf16* packs = aggr_bf + NH;                  // 4 x 16384 bf16
    int* deg = (int*)(packs + 4 * 16384);          // N
    int* ell = deg + N_NODES;                      // N*MAXW (10.24 MB)
    __bf16* pk_in0 = packs;
    __bf16* pk_rec0 = packs + 16384;
    __bf16* pk_in1 = packs + 2 * 16384;
    __bf16* pk_rec1 = packs + 3 * 16384;

    init_kernel<<<N_EDGES / 256, 256, 0, stream>>>(ell, deg, state_bf + NH);
    build_ell_kernel<<<N_EDGES / 256, 256, 0, stream>>>(ei, deg, ell);
    pack_w_kernel<<<64, 256, 0, stream>>>(w_in0, pk_in0, 1);   // B = w_in0^T
    pack_w_kernel<<<64, 256, 0, stream>>>(w_rec0, pk_rec0, 0); // B = w_rec0
    pack_w_kernel<<<64, 256, 0, stream>>>(w_in1, pk_in1, 1);
    pack_w_kernel<<<64, 256, 0, stream>>>(w_rec1, pk_rec1, 0);
    cast_bf16_kernel<<<NH / 4 / 256, 256, 0, stream>>>(x, aggr_bf);  // x_bf in aggr slot

    // ---- layer 0 ----
    mfma_gemm_kernel<<<625, 256, 0, stream>>>(aggr_bf, pk_in0, nullptr, xproj,
                                              state_bf, nullptr);
    for (int it = 0; it < ITERS; ++it) {
        agg_kernel<<<N_NODES / 4, 256, 0, stream>>>(state_bf, ell, deg, aggr_bf);
        mfma_gemm_kernel<<<625, 256, 0, stream>>>(aggr_bf, pk_rec0, xproj, nullptr,
                                                  state_bf, nullptr);
    }
    // ---- layer 1 ----
    mfma_gemm_kernel<<<625, 256, 0, stream>>>(state_bf, pk_in1, nullptr, xproj,
                                              state_bf, nullptr);
    for (int it = 0; it < ITERS; ++it) {
        agg_kernel<<<N_NODES / 4, 256, 0, stream>>>(state_bf, ell, deg, aggr_bf);
        float* f32out = (it == ITERS - 1) ? out : nullptr;
        mfma_gemm_kernel<<<625, 256, 0, stream>>>(aggr_bf, pk_rec1, xproj, nullptr,
                                                  state_bf, f32out);
    }
}